// Round 2
// baseline (1141.447 us; speedup 1.0000x reference)
//
#include <hip/hip_runtime.h>
#include <math.h>

#define FDIM 64
#define RDIM 16
#define LN2F 0.69314718055994530942f

// Numerically stable softplus
__device__ __forceinline__ float sp(float x) {
    return fmaxf(x, 0.0f) + log1pf(__expf(-fabsf(x)));
}

// ---------------- per-atom kernels ----------------

// x = sp(emb)-ln2; v = sp(x@Wi+bi); y = sp(x@Wj+bj)
__global__ __launch_bounds__(256) void k_atoms(
    const float* __restrict__ emb,
    const float* __restrict__ Wi, const float* __restrict__ bi,
    const float* __restrict__ Wj, const float* __restrict__ bj,
    float* __restrict__ v, float* __restrict__ y, int N)
{
    const int c = threadIdx.x & 63;
    const int g = threadIdx.x >> 6;
    float wi[FDIM], wj[FDIM];
#pragma unroll
    for (int k = 0; k < FDIM; ++k) {
        wi[k] = Wi[k * FDIM + c];
        wj[k] = Wj[k * FDIM + c];
    }
    const float bic = bi[c], bjc = bj[c];
    __shared__ __align__(16) float xs[4][FDIM];
    const int stride = gridDim.x * 4;
    for (int a0 = blockIdx.x * 4; a0 < N; a0 += stride) {
        const int a = a0 + g;
        float xv = 0.0f;
        if (a < N) xv = sp(emb[a * FDIM + c]) - LN2F;
        __syncthreads();
        xs[g][c] = xv;
        __syncthreads();
        if (a < N) {
            float acci = bic, accj = bjc;
            const float4* xr = (const float4*)xs[g];
#pragma unroll
            for (int k4 = 0; k4 < FDIM / 4; ++k4) {
                float4 xk = xr[k4];
                acci = fmaf(xk.x, wi[4 * k4 + 0], acci);
                accj = fmaf(xk.x, wj[4 * k4 + 0], accj);
                acci = fmaf(xk.y, wi[4 * k4 + 1], acci);
                accj = fmaf(xk.y, wj[4 * k4 + 1], accj);
                acci = fmaf(xk.z, wi[4 * k4 + 2], acci);
                accj = fmaf(xk.z, wj[4 * k4 + 2], accj);
                acci = fmaf(xk.w, wi[4 * k4 + 3], acci);
                accj = fmaf(xk.w, wj[4 * k4 + 3], accj);
            }
            v[a * FDIM + c] = sp(acci);
            y[a * FDIM + c] = sp(accj);
        }
    }
}

// one residual block: v += sp(v@W1+b1)@W2 + b2
__global__ __launch_bounds__(256) void k_res(
    const float* __restrict__ W1, const float* __restrict__ b1,
    const float* __restrict__ W2, const float* __restrict__ b2,
    float* __restrict__ v, int N)
{
    const int c = threadIdx.x & 63;
    const int g = threadIdx.x >> 6;
    float w1[FDIM], w2[FDIM];
#pragma unroll
    for (int k = 0; k < FDIM; ++k) {
        w1[k] = W1[k * FDIM + c];
        w2[k] = W2[k * FDIM + c];
    }
    const float b1c = b1[c], b2c = b2[c];
    __shared__ __align__(16) float vs[4][FDIM];
    __shared__ __align__(16) float hs[4][FDIM];
    const int stride = gridDim.x * 4;
    for (int a0 = blockIdx.x * 4; a0 < N; a0 += stride) {
        const int a = a0 + g;
        float vv = 0.0f;
        if (a < N) vv = v[a * FDIM + c];
        __syncthreads();
        vs[g][c] = vv;
        __syncthreads();
        float acc = b1c;
        {
            const float4* vr = (const float4*)vs[g];
#pragma unroll
            for (int k4 = 0; k4 < FDIM / 4; ++k4) {
                float4 xk = vr[k4];
                acc = fmaf(xk.x, w1[4 * k4 + 0], acc);
                acc = fmaf(xk.y, w1[4 * k4 + 1], acc);
                acc = fmaf(xk.z, w1[4 * k4 + 2], acc);
                acc = fmaf(xk.w, w1[4 * k4 + 3], acc);
            }
        }
        __syncthreads();
        hs[g][c] = sp(acc);
        __syncthreads();
        float acc2 = b2c;
        {
            const float4* hr = (const float4*)hs[g];
#pragma unroll
            for (int k4 = 0; k4 < FDIM / 4; ++k4) {
                float4 xk = hr[k4];
                acc2 = fmaf(xk.x, w2[4 * k4 + 0], acc2);
                acc2 = fmaf(xk.y, w2[4 * k4 + 1], acc2);
                acc2 = fmaf(xk.z, w2[4 * k4 + 2], acc2);
                acc2 = fmaf(xk.w, w2[4 * k4 + 3], acc2);
            }
        }
        if (a < N) v[a * FDIM + c] = vv + acc2;
    }
}

// out = sp(v) @ Wv + bv  (in-place: v IS d_out)
__global__ __launch_bounds__(256) void k_final(
    const float* __restrict__ Wv, const float* __restrict__ bv,
    float* __restrict__ v, int N)
{
    const int c = threadIdx.x & 63;
    const int g = threadIdx.x >> 6;
    float wv[FDIM];
#pragma unroll
    for (int k = 0; k < FDIM; ++k) wv[k] = Wv[k * FDIM + c];
    const float bvc = bv[c];
    __shared__ __align__(16) float vs[4][FDIM];
    const int stride = gridDim.x * 4;
    for (int a0 = blockIdx.x * 4; a0 < N; a0 += stride) {
        const int a = a0 + g;
        float vv = 0.0f;
        if (a < N) vv = sp(v[a * FDIM + c]);
        __syncthreads();
        vs[g][c] = vv;
        __syncthreads();
        float acc = bvc;
        const float4* vr = (const float4*)vs[g];
#pragma unroll
        for (int k4 = 0; k4 < FDIM / 4; ++k4) {
            float4 xk = vr[k4];
            acc = fmaf(xk.x, wv[4 * k4 + 0], acc);
            acc = fmaf(xk.y, wv[4 * k4 + 1], acc);
            acc = fmaf(xk.z, wv[4 * k4 + 2], acc);
            acc = fmaf(xk.w, wv[4 * k4 + 3], acc);
        }
        if (a < N) v[a * FDIM + c] = acc;
    }
}

// ---------------- pair path A: counting sort + segment sum ----------------

__global__ __launch_bounds__(256) void k_hist(
    const int* __restrict__ idx_i, int* __restrict__ cnt, int P)
{
    int t = blockIdx.x * blockDim.x + threadIdx.x;
    int n = gridDim.x * blockDim.x;
    for (int p = t; p < P; p += n) atomicAdd(&cnt[idx_i[p]], 1);
}

__global__ __launch_bounds__(256) void k_scan_a(
    const int* __restrict__ cnt, int* __restrict__ part, int N)
{
    __shared__ int red[256];
    int b = blockIdx.x, t = threadIdx.x;
    int base = b * 1024 + t * 4;
    int s = 0;
#pragma unroll
    for (int i = 0; i < 4; ++i) { int a = base + i; if (a < N) s += cnt[a]; }
    red[t] = s; __syncthreads();
    for (int off = 128; off > 0; off >>= 1) {
        if (t < off) red[t] += red[t + off];
        __syncthreads();
    }
    if (t == 0) part[b] = red[0];
}

__global__ __launch_bounds__(256) void k_scan_b(int* __restrict__ part, int nPart)
{
    __shared__ int lds[256];
    int t = threadIdx.x;
    int base = t * 4;
    int v[4]; int s = 0;
#pragma unroll
    for (int i = 0; i < 4; ++i) { v[i] = (base + i < nPart) ? part[base + i] : 0; s += v[i]; }
    lds[t] = s; __syncthreads();
    int run = s;
    for (int off = 1; off < 256; off <<= 1) {
        int x = (t >= off) ? lds[t - off] : 0;
        __syncthreads();
        lds[t] += x;
        __syncthreads();
    }
    int excl = lds[t] - run;
#pragma unroll
    for (int i = 0; i < 4; ++i) { if (base + i < nPart) { part[base + i] = excl; excl += v[i]; } }
}

__global__ __launch_bounds__(256) void k_scan_c(
    const int* __restrict__ cnt, const int* __restrict__ part,
    int* __restrict__ start, int* __restrict__ cursor, int N, int P)
{
    __shared__ int lds[256];
    int b = blockIdx.x, t = threadIdx.x;
    int base = b * 1024 + t * 4;
    int v[4]; int s = 0;
#pragma unroll
    for (int i = 0; i < 4; ++i) { int a = base + i; v[i] = (a < N) ? cnt[a] : 0; s += v[i]; }
    lds[t] = s; __syncthreads();
    int run = s;
    for (int off = 1; off < 256; off <<= 1) {
        int x = (t >= off) ? lds[t - off] : 0;
        __syncthreads();
        lds[t] += x;
        __syncthreads();
    }
    int pre = part[b] + (lds[t] - run);
#pragma unroll
    for (int i = 0; i < 4; ++i) {
        int a = base + i;
        if (a < N) { start[a] = pre; cursor[a] = pre; pre += v[i]; }
    }
    if (b == 0 && t == 0) start[N] = P;
}

__global__ __launch_bounds__(256) void k_scatter(
    const int* __restrict__ pidx, int* __restrict__ cursor,
    int2* __restrict__ sorted, int P)
{
    int t = blockIdx.x * blockDim.x + threadIdx.x;
    int n = gridDim.x * blockDim.x;
    for (int p = t; p < P; p += n) {
        int i = pidx[p], j = pidx[P + p];
        int pos = atomicAdd(&cursor[i], 1);
        sorted[pos] = make_int2(p, j);
    }
}

// one wave per atom: v[a] += sum over its pairs of (f[p]@G[c]) * y[j][c]
__global__ __launch_bounds__(256) void k_seg(
    const int2* __restrict__ sorted, const int* __restrict__ start,
    const float* __restrict__ f_ij, const float* __restrict__ G,
    const float* __restrict__ y, float* __restrict__ v, int N)
{
    const int c = threadIdx.x & 63;
    const int w = (blockIdx.x << 2) | (threadIdx.x >> 6);
    const int nw = gridDim.x << 2;
    float4 g0, g1, g2, g3;
    {
        const float4* gp = (const float4*)(G + c * RDIM);
        g0 = gp[0]; g1 = gp[1]; g2 = gp[2]; g3 = gp[3];
    }
    for (int a = w; a < N; a += nw) {
        const int s = start[a], e = start[a + 1];
        float acc = 0.0f;
        int q = s;
        for (; q + 2 <= e; q += 2) {
            int2 e0 = sorted[q], e1 = sorted[q + 1];
            const float4* f0 = (const float4*)(f_ij + (long)e0.x * RDIM);
            const float4* f1 = (const float4*)(f_ij + (long)e1.x * RDIM);
            float4 a0 = f0[0], a1 = f0[1], a2 = f0[2], a3 = f0[3];
            float4 b0 = f1[0], b1 = f1[1], b2 = f1[2], b3 = f1[3];
            float y0 = y[(long)e0.y * FDIM + c];
            float y1 = y[(long)e1.y * FDIM + c];
            float d0 = a0.x * g0.x;
            d0 = fmaf(a0.y, g0.y, d0); d0 = fmaf(a0.z, g0.z, d0); d0 = fmaf(a0.w, g0.w, d0);
            d0 = fmaf(a1.x, g1.x, d0); d0 = fmaf(a1.y, g1.y, d0); d0 = fmaf(a1.z, g1.z, d0); d0 = fmaf(a1.w, g1.w, d0);
            d0 = fmaf(a2.x, g2.x, d0); d0 = fmaf(a2.y, g2.y, d0); d0 = fmaf(a2.z, g2.z, d0); d0 = fmaf(a2.w, g2.w, d0);
            d0 = fmaf(a3.x, g3.x, d0); d0 = fmaf(a3.y, g3.y, d0); d0 = fmaf(a3.z, g3.z, d0); d0 = fmaf(a3.w, g3.w, d0);
            float d1 = b0.x * g0.x;
            d1 = fmaf(b0.y, g0.y, d1); d1 = fmaf(b0.z, g0.z, d1); d1 = fmaf(b0.w, g0.w, d1);
            d1 = fmaf(b1.x, g1.x, d1); d1 = fmaf(b1.y, g1.y, d1); d1 = fmaf(b1.z, g1.z, d1); d1 = fmaf(b1.w, g1.w, d1);
            d1 = fmaf(b2.x, g2.x, d1); d1 = fmaf(b2.y, g2.y, d1); d1 = fmaf(b2.z, g2.z, d1); d1 = fmaf(b2.w, g2.w, d1);
            d1 = fmaf(b3.x, g3.x, d1); d1 = fmaf(b3.y, g3.y, d1); d1 = fmaf(b3.z, g3.z, d1); d1 = fmaf(b3.w, g3.w, d1);
            acc = fmaf(d0, y0, acc);
            acc = fmaf(d1, y1, acc);
        }
        if (q < e) {
            int2 e0 = sorted[q];
            const float4* f0 = (const float4*)(f_ij + (long)e0.x * RDIM);
            float4 a0 = f0[0], a1 = f0[1], a2 = f0[2], a3 = f0[3];
            float y0 = y[(long)e0.y * FDIM + c];
            float d0 = a0.x * g0.x;
            d0 = fmaf(a0.y, g0.y, d0); d0 = fmaf(a0.z, g0.z, d0); d0 = fmaf(a0.w, g0.w, d0);
            d0 = fmaf(a1.x, g1.x, d0); d0 = fmaf(a1.y, g1.y, d0); d0 = fmaf(a1.z, g1.z, d0); d0 = fmaf(a1.w, g1.w, d0);
            d0 = fmaf(a2.x, g2.x, d0); d0 = fmaf(a2.y, g2.y, d0); d0 = fmaf(a2.z, g2.z, d0); d0 = fmaf(a2.w, g2.w, d0);
            d0 = fmaf(a3.x, g3.x, d0); d0 = fmaf(a3.y, g3.y, d0); d0 = fmaf(a3.z, g3.z, d0); d0 = fmaf(a3.w, g3.w, d0);
            acc = fmaf(d0, y0, acc);
        }
        v[(long)a * FDIM + c] += acc;
    }
}

// ---------------- pair path B (fallback): per-pair atomics ----------------

__global__ __launch_bounds__(256) void k_pairs(
    const int* __restrict__ pidx, const float* __restrict__ f_ij,
    const float* __restrict__ G, const float* __restrict__ y,
    float* __restrict__ v, int P)
{
    const int c = threadIdx.x & 63;
    const int wave = (blockIdx.x << 2) | (threadIdx.x >> 6);
    const int nw = gridDim.x << 2;
    float4 gr[RDIM / 4];
    const float4* gp = (const float4*)(G + c * RDIM);
#pragma unroll
    for (int r4 = 0; r4 < RDIM / 4; ++r4) gr[r4] = gp[r4];
    const int* idx_i = pidx;
    const int* idx_j = pidx + P;
    const int per = (P + nw - 1) / nw;
    int p0 = wave * per;
    int p1 = p0 + per; if (p1 > P) p1 = P;
    for (int p = p0; p < p1; ++p) {
        const int i = idx_i[p];
        const int j = idx_j[p];
        const float4* fr = (const float4*)(f_ij + p * RDIM);
        float acc = 0.0f;
#pragma unroll
        for (int r4 = 0; r4 < RDIM / 4; ++r4) {
            float4 f4 = fr[r4];
            acc = fmaf(f4.x, gr[r4].x, acc);
            acc = fmaf(f4.y, gr[r4].y, acc);
            acc = fmaf(f4.z, gr[r4].z, acc);
            acc = fmaf(f4.w, gr[r4].w, acc);
        }
        atomicAdd(&v[i * FDIM + c], acc * y[j * FDIM + c]);
    }
}

extern "C" void kernel_launch(void* const* d_in, const int* in_sizes, int n_in,
                              void* d_out, int out_size, void* d_ws, size_t ws_size,
                              hipStream_t stream)
{
    const int*   pidx = (const int*)d_in[0];    // [2, P]
    const float* f_ij = (const float*)d_in[1];  // [P, 1, R]
    const float* emb  = (const float*)d_in[3];  // [N, F]
    const float* G    = (const float*)d_in[4];  // [F, R]
    const float* Wi   = (const float*)d_in[5];
    const float* bi   = (const float*)d_in[6];
    const float* Wj   = (const float*)d_in[7];
    const float* bj   = (const float*)d_in[8];
    const float* rW1  = (const float*)d_in[9];
    const float* rb1  = (const float*)d_in[10];
    const float* rW2  = (const float*)d_in[11];
    const float* rb2  = (const float*)d_in[12];
    const float* Wv   = (const float*)d_in[13];
    const float* bv   = (const float*)d_in[14];

    const int P = in_sizes[0] / 2;
    const int N = in_sizes[3] / FDIM;

    float* v = (float*)d_out;

    // workspace layout
    char* ws = (char*)d_ws;
    size_t off = 0;
    float* y      = (float*)(ws + off); off += (size_t)N * FDIM * 4;
    int*   cnt    = (int*)(ws + off);   off += (size_t)N * 4;
    int*   start  = (int*)(ws + off);   off += (size_t)(N + 1) * 4;
    int*   cursor = (int*)(ws + off);   off += (size_t)N * 4;
    off = (off + 15) & ~(size_t)15;
    int*   part   = (int*)(ws + off);   off += (size_t)4096 * 4;
    off = (off + 15) & ~(size_t)15;
    int2*  sorted = (int2*)(ws + off);  off += (size_t)P * 8;

    const int nPart = (N + 1023) / 1024;
    const bool sortOK = (off <= ws_size) && (nPart <= 1024);

    dim3 blk(256);
    k_atoms<<<512, blk, 0, stream>>>(emb, Wi, bi, Wj, bj, v, y, N);

    if (sortOK) {
        hipMemsetAsync(cnt, 0, (size_t)N * 4, stream);
        k_hist<<<1024, blk, 0, stream>>>(pidx, cnt, P);
        k_scan_a<<<nPart, blk, 0, stream>>>(cnt, part, N);
        k_scan_b<<<1, blk, 0, stream>>>(part, nPart);
        k_scan_c<<<nPart, blk, 0, stream>>>(cnt, part, start, cursor, N, P);
        k_scatter<<<1024, blk, 0, stream>>>(pidx, cursor, sorted, P);
        k_seg<<<4096, blk, 0, stream>>>(sorted, start, f_ij, G, y, v, N);
    } else {
        k_pairs<<<2048, blk, 0, stream>>>(pidx, f_ij, G, y, v, P);
    }

    for (int l = 0; l < 3; ++l) {
        k_res<<<512, blk, 0, stream>>>(rW1 + l * FDIM * FDIM, rb1 + l * FDIM,
                                       rW2 + l * FDIM * FDIM, rb2 + l * FDIM, v, N);
    }
    k_final<<<512, blk, 0, stream>>>(Wv, bv, v, N);
}